// Round 3
// baseline (737.554 us; speedup 1.0000x reference)
//
#include <hip/hip_runtime.h>
#include <hip/hip_bf16.h>

#define LQ 16
#define DD 256
#define LP 4096
#define NBH 256

typedef __attribute__((ext_vector_type(8))) short bf16x8;
typedef __attribute__((ext_vector_type(4))) float f32x4;

static constexpr float QSC = 0.0625f * 1.44269504088896340736f; // D^-0.5 * log2(e)
static constexpr float NEGBIG = -1e30f;
static constexpr float MINIT  = -1e4f;   // exp2(MINIT)==0 in fp32; keeps m-mn finite

__device__ inline unsigned cvt2(float a, float b) {
  unsigned r;
  asm("v_cvt_pk_bf16_f32 %0, %1, %2" : "=v"(r) : "v"(a), "v"(b));
  return r;
}

union FragU { unsigned u[4]; bf16x8 v; };

__device__ inline bf16x8 pack8(float a0,float a1,float a2,float a3,
                               float a4,float a5,float a6,float a7){
  FragU x;
  x.u[0]=cvt2(a0,a1); x.u[1]=cvt2(a2,a3); x.u[2]=cvt2(a4,a5); x.u[3]=cvt2(a6,a7);
  return x.v;
}

// One 32-row K/V chunk of online-softmax attention for one wave.
// Lane layout: q = lane&15, g = lane>>4.
// Scores (swapped mfma(K,Q)): lane holds s for k = k0 + 16*t + 4g + j.
// P fragment slot j <-> k = k0 + 4g + (j&3) + 16*(j>>2) ; V loaded to match.
template<bool ACTIVE>
__device__ inline void chunk_body(const float* __restrict__ kb_bh,
                                  const float* __restrict__ vb_bh,
                                  const unsigned char* __restrict__ m8_bh,
                                  const int* __restrict__ m32_bh,
                                  bool mbool, int k0, int l15, int g, int dh,
                                  const bf16x8 (&qf)[8],
                                  f32x4 (&acc)[8], float& m, float& l)
{
  f32x4 sc0 = {0.f,0.f,0.f,0.f}, sc1 = {0.f,0.f,0.f,0.f};
  {
    const int r0 = ACTIVE ? l15 : (k0 + l15);
    const float* kr0 = kb_bh + (size_t)r0 * DD + 8*g;
    #pragma unroll
    for (int s = 0; s < 8; ++s) {
      float4 a = *(const float4*)(kr0 + 32*s);
      float4 b = *(const float4*)(kr0 + 32*s + 4);
      bf16x8 kf = pack8(a.x,a.y,a.z,a.w,b.x,b.y,b.z,b.w);
      sc0 = __builtin_amdgcn_mfma_f32_16x16x32_bf16(kf, qf[s], sc0, 0,0,0);
    }
  }
  if (!ACTIVE) {
    const float* kr1 = kb_bh + (size_t)(k0 + 16 + l15) * DD + 8*g;
    #pragma unroll
    for (int s = 0; s < 8; ++s) {
      float4 a = *(const float4*)(kr1 + 32*s);
      float4 b = *(const float4*)(kr1 + 32*s + 4);
      bf16x8 kf = pack8(a.x,a.y,a.z,a.w,b.x,b.y,b.z,b.w);
      sc1 = __builtin_amdgcn_mfma_f32_16x16x32_bf16(kf, qf[s], sc1, 0,0,0);
    }
  }

  float s8[8];
  if (!ACTIVE) {
    const int ka0 = k0 + 4*g, ka1 = k0 + 16 + 4*g;
    if (mbool) {
      unsigned w0 = *(const unsigned*)(m8_bh + (size_t)l15*LP + ka0);
      unsigned w1 = *(const unsigned*)(m8_bh + (size_t)l15*LP + ka1);
      #pragma unroll
      for (int j = 0; j < 4; ++j) {
        s8[j]   = ((w0>>(8*j))&0xFFu) ? sc0[j] : NEGBIG;
        s8[4+j] = ((w1>>(8*j))&0xFFu) ? sc1[j] : NEGBIG;
      }
    } else {
      int4 w0 = *(const int4*)(m32_bh + (size_t)l15*LP + ka0);
      int4 w1 = *(const int4*)(m32_bh + (size_t)l15*LP + ka1);
      s8[0]=w0.x?sc0[0]:NEGBIG; s8[1]=w0.y?sc0[1]:NEGBIG;
      s8[2]=w0.z?sc0[2]:NEGBIG; s8[3]=w0.w?sc0[3]:NEGBIG;
      s8[4]=w1.x?sc1[0]:NEGBIG; s8[5]=w1.y?sc1[1]:NEGBIG;
      s8[6]=w1.z?sc1[2]:NEGBIG; s8[7]=w1.w?sc1[3]:NEGBIG;
    }
  } else {
    #pragma unroll
    for (int j = 0; j < 4; ++j) { s8[j] = sc0[j]; s8[4+j] = NEGBIG; }
  }

  // online softmax in exp2 domain (QSC folded log2e into Q)
  float mx = fmaxf(fmaxf(fmaxf(s8[0],s8[1]),fmaxf(s8[2],s8[3])),
                   fmaxf(fmaxf(s8[4],s8[5]),fmaxf(s8[6],s8[7])));
  mx = fmaxf(mx, __shfl_xor(mx,16));
  mx = fmaxf(mx, __shfl_xor(mx,32));
  const float mn = fmaxf(m, mx);
  const float f = __builtin_amdgcn_exp2f(m - mn);
  float p[8], ps = 0.f;
  #pragma unroll
  for (int j = 0; j < 8; ++j){ p[j] = __builtin_amdgcn_exp2f(s8[j]-mn); ps += p[j]; }
  ps += __shfl_xor(ps,16);
  ps += __shfl_xor(ps,32);
  l = l * f + ps;
  m = mn;
  #pragma unroll
  for (int t = 0; t < 8; ++t){ acc[t][0]*=f; acc[t][1]*=f; acc[t][2]*=f; acc[t][3]*=f; }

  bf16x8 pf = pack8(p[0],p[1],p[2],p[3],p[4],p[5],p[6],p[7]);

  int vo[8];
  #pragma unroll
  for (int j = 0; j < 8; ++j) {
    const int kv = 4*g + (j&3) + 16*(j>>2);
    vo[j] = (ACTIVE ? kv : (k0 + kv)) * DD + dh*128 + l15;
  }
  #pragma unroll
  for (int t = 0; t < 8; ++t) {
    float v0 = vb_bh[vo[0]+16*t], v1 = vb_bh[vo[1]+16*t],
          v2 = vb_bh[vo[2]+16*t], v3 = vb_bh[vo[3]+16*t];
    float v4=0.f, v5=0.f, v6=0.f, v7=0.f;
    if (!ACTIVE) { v4 = vb_bh[vo[4]+16*t]; v5 = vb_bh[vo[5]+16*t];
                   v6 = vb_bh[vo[6]+16*t]; v7 = vb_bh[vo[7]+16*t]; }
    bf16x8 vf = pack8(v0,v1,v2,v3,v4,v5,v6,v7);
    acc[t] = __builtin_amdgcn_mfma_f32_16x16x32_bf16(vf, pf, acc[t], 0,0,0);
  }
}

__global__ __launch_bounds__(256, 4)
void attn_main(const float* __restrict__ Q, const float* __restrict__ Kp,
               const float* __restrict__ Vp, const float* __restrict__ Ka,
               const float* __restrict__ Va, const void* __restrict__ mask,
               float* __restrict__ out, float* __restrict__ dn)
{
  const int tid = threadIdx.x;
  const int lane = tid & 63;
  const int wid = tid >> 6;
  const int pair = wid >> 1, dh = wid & 1;
  const int bh = blockIdx.x >> 3;
  const int pg = (blockIdx.x & 7) * 2 + pair;   // pair-global: 0..15 (256 rows each)
  const int l15 = lane & 15, g = lane >> 4;

  // mask dtype probe: bytes 4i+1 are all-zero iff mask is int32-encoded
  const unsigned char* m8all = (const unsigned char*)mask;
  unsigned probe = 0;
  for (int i = lane; i < 256; i += 64) probe |= m8all[4*i+1];
  const bool mbool = (__any(probe != 0) != 0);

  // Q fragments (B-operand), scale folded in
  const float* qb = Q + ((size_t)bh*LQ + l15)*DD + 8*g;
  bf16x8 qf[8];
  #pragma unroll
  for (int s = 0; s < 8; ++s) {
    float4 a = *(const float4*)(qb + 32*s);
    float4 b = *(const float4*)(qb + 32*s + 4);
    qf[s] = pack8(a.x*QSC,a.y*QSC,a.z*QSC,a.w*QSC,
                  b.x*QSC,b.y*QSC,b.z*QSC,b.w*QSC);
  }

  f32x4 acc[8];
  #pragma unroll
  for (int t = 0; t < 8; ++t) acc[t] = (f32x4){0.f,0.f,0.f,0.f};
  float m = MINIT, l = 0.f;

  const float* kb_bh = Kp + (size_t)bh*LP*DD;
  const float* vb_bh = Vp + (size_t)bh*LP*DD;
  const unsigned char* m8_bh = m8all + (size_t)bh*LQ*LP;
  const int* m32_bh = (const int*)mask + (size_t)bh*LQ*LP;

  const int kbase = pg * 256;
  for (int c = 0; c < 8; ++c)
    chunk_body<false>(kb_bh, vb_bh, m8_bh, m32_bh, mbool,
                      kbase + 32*c, l15, g, dh, qf, acc, m, l);

  if (pg == 0)   // active K/V: one extra unmasked 16-row chunk
    chunk_body<true>(Ka + (size_t)bh*LQ*DD, Va + (size_t)bh*LQ*DD,
                     nullptr, nullptr, mbool, 0, l15, g, dh, qf, acc, m, l);

  // merge via fixed reference point R=0: logits*log2e is O(10), exp2 safe
  const float w = __builtin_amdgcn_exp2f(m);
  float* ob = out + ((size_t)bh*LQ + l15)*DD + dh*128 + 4*g;
  #pragma unroll
  for (int t = 0; t < 8; ++t) {
    atomicAdd(ob + 16*t + 0, w*acc[t][0]);
    atomicAdd(ob + 16*t + 1, w*acc[t][1]);
    atomicAdd(ob + 16*t + 2, w*acc[t][2]);
    atomicAdd(ob + 16*t + 3, w*acc[t][3]);
  }
  if (dh == 0 && g == 0)
    atomicAdd(dn + bh*LQ + l15, w*l);
}

__global__ void attn_norm(float* __restrict__ out, const float* __restrict__ dn)
{
  const int e = blockIdx.x * 256 + threadIdx.x;
  out[e] = out[e] / dn[e >> 8];
}

extern "C" void kernel_launch(void* const* d_in, const int* in_sizes, int n_in,
                              void* d_out, int out_size, void* d_ws, size_t ws_size,
                              hipStream_t stream) {
  const float* Q  = (const float*)d_in[0];
  const float* Kp = (const float*)d_in[1];
  const float* Vp = (const float*)d_in[2];
  const float* Ka = (const float*)d_in[3];
  const float* Va = (const float*)d_in[4];
  const void* mask = d_in[5];
  float* out = (float*)d_out;
  float* dn  = (float*)d_ws;   // 256*16 floats = 16 KB

  hipMemsetAsync(out, 0, (size_t)out_size * sizeof(float), stream);
  hipMemsetAsync(dn, 0, NBH * LQ * sizeof(float), stream);
  attn_main<<<NBH*8, 256, 0, stream>>>(Q, Kp, Vp, Ka, Va, mask, out, dn);
  attn_norm<<<(NBH*LQ*DD)/256, 256, 0, stream>>>(out, dn);
}

// Round 8
// 583.386 us; speedup vs baseline: 1.2643x; 1.2643x over previous
//
#include <hip/hip_runtime.h>
#include <hip/hip_bf16.h>

#define LQ 16
#define DD 256
#define LP 4096
#define NBH 256

typedef __attribute__((ext_vector_type(8))) short bf16x8;
typedef __attribute__((ext_vector_type(4))) float f32x4;

static constexpr float QSC = 0.0625f * 1.44269504088896340736f; // D^-0.5 * log2(e)
static constexpr float NEGBIG = -1e30f;
static constexpr float MINIT  = -1e4f;   // exp2(MINIT)==0 in fp32; keeps m-mn finite

__device__ inline unsigned cvt2(float a, float b) {
  unsigned r;
  asm("v_cvt_pk_bf16_f32 %0, %1, %2" : "=v"(r) : "v"(a), "v"(b));
  return r;
}

union FragU { unsigned u[4]; bf16x8 v; };

__device__ inline bf16x8 pack8(float a0,float a1,float a2,float a3,
                               float a4,float a5,float a6,float a7){
  FragU x;
  x.u[0]=cvt2(a0,a1); x.u[1]=cvt2(a2,a3); x.u[2]=cvt2(a4,a5); x.u[3]=cvt2(a6,a7);
  return x.v;
}

// One 32-row K/V chunk of online-softmax attention for one wave.
// Lane layout: q = lane&15, g = lane>>4.
// Scores (swapped mfma(K,Q)): lane holds s for k = k0 + 16*t + 4g + j.
// P fragment slot j <-> k = k0 + 4g + (j&3) + 16*(j>>2) ; V loaded to match.
// R8 delta vs R1: V loads for t=0..3 hoisted before softmax (latency hiding),
// everything else identical to the R1/R3 passing structure.
template<bool ACTIVE>
__device__ inline void chunk_body(const float* __restrict__ kb_bh,
                                  const float* __restrict__ vb_bh,
                                  const unsigned char* __restrict__ m8_bh,
                                  const int* __restrict__ m32_bh,
                                  bool mbool, int k0, int l15, int g, int dh,
                                  const bf16x8 (&qf)[8],
                                  f32x4 (&acc)[8], float& m, float& l)
{
  f32x4 sc0 = {0.f,0.f,0.f,0.f}, sc1 = {0.f,0.f,0.f,0.f};
  {
    const int r0 = ACTIVE ? l15 : (k0 + l15);
    const float* kr0 = kb_bh + (size_t)r0 * DD + 8*g;
    #pragma unroll
    for (int s = 0; s < 8; ++s) {
      float4 a = *(const float4*)(kr0 + 32*s);
      float4 b = *(const float4*)(kr0 + 32*s + 4);
      bf16x8 kf = pack8(a.x,a.y,a.z,a.w,b.x,b.y,b.z,b.w);
      sc0 = __builtin_amdgcn_mfma_f32_16x16x32_bf16(kf, qf[s], sc0, 0,0,0);
    }
  }
  if (!ACTIVE) {
    const float* kr1 = kb_bh + (size_t)(k0 + 16 + l15) * DD + 8*g;
    #pragma unroll
    for (int s = 0; s < 8; ++s) {
      float4 a = *(const float4*)(kr1 + 32*s);
      float4 b = *(const float4*)(kr1 + 32*s + 4);
      bf16x8 kf = pack8(a.x,a.y,a.z,a.w,b.x,b.y,b.z,b.w);
      sc1 = __builtin_amdgcn_mfma_f32_16x16x32_bf16(kf, qf[s], sc1, 0,0,0);
    }
  }

  int vo[8];
  #pragma unroll
  for (int j = 0; j < 8; ++j) {
    const int kv = 4*g + (j&3) + 16*(j>>2);
    vo[j] = (ACTIVE ? kv : (k0 + kv)) * DD + dh*128 + l15;
  }

  // ---- hoisted V loads, first half (t=0..3): fly during mask+softmax ----
  float vv[4][8];
  #pragma unroll
  for (int t = 0; t < 4; ++t) {
    #pragma unroll
    for (int j = 0; j < 8; ++j) {
      if (!ACTIVE || j < 4) vv[t][j] = vb_bh[vo[j] + 16*t];
      else                  vv[t][j] = 0.f;
    }
  }

  float s8[8];
  if (!ACTIVE) {
    const int ka0 = k0 + 4*g, ka1 = k0 + 16 + 4*g;
    if (mbool) {
      unsigned w0 = *(const unsigned*)(m8_bh + (size_t)l15*LP + ka0);
      unsigned w1 = *(const unsigned*)(m8_bh + (size_t)l15*LP + ka1);
      #pragma unroll
      for (int j = 0; j < 4; ++j) {
        s8[j]   = ((w0>>(8*j))&0xFFu) ? sc0[j] : NEGBIG;
        s8[4+j] = ((w1>>(8*j))&0xFFu) ? sc1[j] : NEGBIG;
      }
    } else {
      int4 w0 = *(const int4*)(m32_bh + (size_t)l15*LP + ka0);
      int4 w1 = *(const int4*)(m32_bh + (size_t)l15*LP + ka1);
      s8[0]=w0.x?sc0[0]:NEGBIG; s8[1]=w0.y?sc0[1]:NEGBIG;
      s8[2]=w0.z?sc0[2]:NEGBIG; s8[3]=w0.w?sc0[3]:NEGBIG;
      s8[4]=w1.x?sc1[0]:NEGBIG; s8[5]=w1.y?sc1[1]:NEGBIG;
      s8[6]=w1.z?sc1[2]:NEGBIG; s8[7]=w1.w?sc1[3]:NEGBIG;
    }
  } else {
    #pragma unroll
    for (int j = 0; j < 4; ++j) { s8[j] = sc0[j]; s8[4+j] = NEGBIG; }
  }

  // online softmax in exp2 domain (QSC folded log2e into Q)
  float mx = fmaxf(fmaxf(fmaxf(s8[0],s8[1]),fmaxf(s8[2],s8[3])),
                   fmaxf(fmaxf(s8[4],s8[5]),fmaxf(s8[6],s8[7])));
  mx = fmaxf(mx, __shfl_xor(mx,16));
  mx = fmaxf(mx, __shfl_xor(mx,32));
  const float mn = fmaxf(m, mx);
  const float f = __builtin_amdgcn_exp2f(m - mn);
  float p[8], ps = 0.f;
  #pragma unroll
  for (int j = 0; j < 8; ++j){ p[j] = __builtin_amdgcn_exp2f(s8[j]-mn); ps += p[j]; }
  ps += __shfl_xor(ps,16);
  ps += __shfl_xor(ps,32);
  l = l * f + ps;
  m = mn;
  #pragma unroll
  for (int t = 0; t < 8; ++t){ acc[t][0]*=f; acc[t][1]*=f; acc[t][2]*=f; acc[t][3]*=f; }

  bf16x8 pf = pack8(p[0],p[1],p[2],p[3],p[4],p[5],p[6],p[7]);

  // ---- PV: t=0..3 from staged regs, t=4..7 direct loads (as R1) ----
  #pragma unroll
  for (int t = 0; t < 4; ++t) {
    bf16x8 vf = pack8(vv[t][0],vv[t][1],vv[t][2],vv[t][3],
                      vv[t][4],vv[t][5],vv[t][6],vv[t][7]);
    acc[t] = __builtin_amdgcn_mfma_f32_16x16x32_bf16(vf, pf, acc[t], 0,0,0);
  }
  #pragma unroll
  for (int t = 4; t < 8; ++t) {
    float v0 = vb_bh[vo[0]+16*t], v1 = vb_bh[vo[1]+16*t],
          v2 = vb_bh[vo[2]+16*t], v3 = vb_bh[vo[3]+16*t];
    float v4=0.f, v5=0.f, v6=0.f, v7=0.f;
    if (!ACTIVE) { v4 = vb_bh[vo[4]+16*t]; v5 = vb_bh[vo[5]+16*t];
                   v6 = vb_bh[vo[6]+16*t]; v7 = vb_bh[vo[7]+16*t]; }
    bf16x8 vf = pack8(v0,v1,v2,v3,v4,v5,v6,v7);
    acc[t] = __builtin_amdgcn_mfma_f32_16x16x32_bf16(vf, pf, acc[t], 0,0,0);
  }
}

__global__ __launch_bounds__(256, 4)
void attn_main(const float* __restrict__ Q, const float* __restrict__ Kp,
               const float* __restrict__ Vp, const float* __restrict__ Ka,
               const float* __restrict__ Va, const void* __restrict__ mask,
               float* __restrict__ out, float* __restrict__ dn)
{
  const int tid = threadIdx.x;
  const int lane = tid & 63;
  const int wid = tid >> 6;
  const int pair = wid >> 1, dh = wid & 1;
  const int bh = blockIdx.x >> 2;
  const int pg = (blockIdx.x & 3) * 2 + pair;   // pair-global: 0..7 (512 rows each)
  const int l15 = lane & 15, g = lane >> 4;

  // mask dtype probe: bytes 4i+1 are all-zero iff mask is int32-encoded
  const unsigned char* m8all = (const unsigned char*)mask;
  unsigned probe = 0;
  for (int i = lane; i < 256; i += 64) probe |= m8all[4*i+1];
  const bool mbool = (__any(probe != 0) != 0);

  // Q fragments (B-operand), scale folded in
  const float* qb = Q + ((size_t)bh*LQ + l15)*DD + 8*g;
  bf16x8 qf[8];
  #pragma unroll
  for (int s = 0; s < 8; ++s) {
    float4 a = *(const float4*)(qb + 32*s);
    float4 b = *(const float4*)(qb + 32*s + 4);
    qf[s] = pack8(a.x*QSC,a.y*QSC,a.z*QSC,a.w*QSC,
                  b.x*QSC,b.y*QSC,b.z*QSC,b.w*QSC);
  }

  f32x4 acc[8];
  #pragma unroll
  for (int t = 0; t < 8; ++t) acc[t] = (f32x4){0.f,0.f,0.f,0.f};
  float m = MINIT, l = 0.f;

  const float* kb_bh = Kp + (size_t)bh*LP*DD;
  const float* vb_bh = Vp + (size_t)bh*LP*DD;
  const unsigned char* m8_bh = m8all + (size_t)bh*LQ*LP;
  const int* m32_bh = (const int*)mask + (size_t)bh*LQ*LP;

  const int kbase = pg * 512;
  for (int c = 0; c < 16; ++c)
    chunk_body<false>(kb_bh, vb_bh, m8_bh, m32_bh, mbool,
                      kbase + 32*c, l15, g, dh, qf, acc, m, l);

  if (pg == 0)   // active K/V: one extra unmasked 16-row chunk
    chunk_body<true>(Ka + (size_t)bh*LQ*DD, Va + (size_t)bh*LQ*DD,
                     nullptr, nullptr, mbool, 0, l15, g, dh, qf, acc, m, l);

  // merge via fixed reference point R=0: logits*log2e is O(10), exp2 safe
  const float w = __builtin_amdgcn_exp2f(m);
  float* ob = out + ((size_t)bh*LQ + l15)*DD + dh*128 + 4*g;
  #pragma unroll
  for (int t = 0; t < 8; ++t) {
    atomicAdd(ob + 16*t + 0, w*acc[t][0]);
    atomicAdd(ob + 16*t + 1, w*acc[t][1]);
    atomicAdd(ob + 16*t + 2, w*acc[t][2]);
    atomicAdd(ob + 16*t + 3, w*acc[t][3]);
  }
  if (dh == 0 && g == 0)
    atomicAdd(dn + bh*LQ + l15, w*l);
}

__global__ void attn_norm(float* __restrict__ out, const float* __restrict__ dn)
{
  const int e = blockIdx.x * 256 + threadIdx.x;
  out[e] = out[e] / dn[e >> 8];
}

extern "C" void kernel_launch(void* const* d_in, const int* in_sizes, int n_in,
                              void* d_out, int out_size, void* d_ws, size_t ws_size,
                              hipStream_t stream) {
  const float* Q  = (const float*)d_in[0];
  const float* Kp = (const float*)d_in[1];
  const float* Vp = (const float*)d_in[2];
  const float* Ka = (const float*)d_in[3];
  const float* Va = (const float*)d_in[4];
  const void* mask = d_in[5];
  float* out = (float*)d_out;
  float* dn  = (float*)d_ws;   // 256*16 floats = 16 KB

  hipMemsetAsync(out, 0, (size_t)out_size * sizeof(float), stream);
  hipMemsetAsync(dn, 0, NBH * LQ * sizeof(float), stream);
  attn_main<<<NBH*4, 256, 0, stream>>>(Q, Kp, Vp, Ka, Va, mask, out, dn);
  attn_norm<<<(NBH*LQ*DD)/256, 256, 0, stream>>>(out, dn);
}

// Round 10
// 545.851 us; speedup vs baseline: 1.3512x; 1.0688x over previous
//
#include <hip/hip_runtime.h>
#include <hip/hip_bf16.h>

#define LQ 16
#define DD 256
#define LP 4096
#define NBH 256

typedef __attribute__((ext_vector_type(8))) short bf16x8;
typedef __attribute__((ext_vector_type(4))) float f32x4;

static constexpr float QSC = 0.0625f * 1.44269504088896340736f; // D^-0.5 * log2(e)
static constexpr float NEGBIG = -1e30f;
static constexpr float MINIT  = -1e4f;   // exp2(MINIT)==0 in fp32; keeps m-mn finite

__device__ inline unsigned cvt2(float a, float b) {
  unsigned r;
  asm("v_cvt_pk_bf16_f32 %0, %1, %2" : "=v"(r) : "v"(a), "v"(b));
  return r;
}

union FragU { unsigned u[4]; bf16x8 v; };

__device__ inline bf16x8 pack8(float a0,float a1,float a2,float a3,
                               float a4,float a5,float a6,float a7){
  FragU x;
  x.u[0]=cvt2(a0,a1); x.u[1]=cvt2(a2,a3); x.u[2]=cvt2(a4,a5); x.u[3]=cvt2(a6,a7);
  return x.v;
}

// One 32-row K/V chunk of online-softmax attention for one wave.
// Lane layout: q = lane&15, g = lane>>4.
// Scores (swapped mfma(K,Q)): lane holds s for k = k0 + 16*t + 4g + j.
// P fragment slot j <-> k = k0 + 4g + (j&3) + 16*(j>>2) ; V loaded to match.
// R10 delta vs R8: ALL V t-groups hoisted before softmax, but staged as bf16
// fragments (4 regs/group, 32 total) instead of fp32 (64) so the kernel stays
// inside the proven (256,4)/<=128-reg regime. K path identical to R8.
template<bool ACTIVE>
__device__ inline void chunk_body(const float* __restrict__ kb_bh,
                                  const float* __restrict__ vb_bh,
                                  const unsigned char* __restrict__ m8_bh,
                                  const int* __restrict__ m32_bh,
                                  bool mbool, int k0, int l15, int g, int dh,
                                  const bf16x8 (&qf)[8],
                                  f32x4 (&acc)[8], float& m, float& l)
{
  f32x4 sc0 = {0.f,0.f,0.f,0.f}, sc1 = {0.f,0.f,0.f,0.f};
  {
    const int r0 = ACTIVE ? l15 : (k0 + l15);
    const float* kr0 = kb_bh + (size_t)r0 * DD + 8*g;
    #pragma unroll
    for (int s = 0; s < 8; ++s) {
      float4 a = *(const float4*)(kr0 + 32*s);
      float4 b = *(const float4*)(kr0 + 32*s + 4);
      bf16x8 kf = pack8(a.x,a.y,a.z,a.w,b.x,b.y,b.z,b.w);
      sc0 = __builtin_amdgcn_mfma_f32_16x16x32_bf16(kf, qf[s], sc0, 0,0,0);
    }
  }
  if (!ACTIVE) {
    const float* kr1 = kb_bh + (size_t)(k0 + 16 + l15) * DD + 8*g;
    #pragma unroll
    for (int s = 0; s < 8; ++s) {
      float4 a = *(const float4*)(kr1 + 32*s);
      float4 b = *(const float4*)(kr1 + 32*s + 4);
      bf16x8 kf = pack8(a.x,a.y,a.z,a.w,b.x,b.y,b.z,b.w);
      sc1 = __builtin_amdgcn_mfma_f32_16x16x32_bf16(kf, qf[s], sc1, 0,0,0);
    }
  }

  int vo[8];
  #pragma unroll
  for (int j = 0; j < 8; ++j) {
    const int kv = 4*g + (j&3) + 16*(j>>2);
    vo[j] = (ACTIVE ? kv : (k0 + kv)) * DD + dh*128 + l15;
  }

  // ---- hoisted V, ALL t-groups, staged as bf16 fragments (4 regs each) ----
  bf16x8 vfr[8];
  #pragma unroll
  for (int t = 0; t < 8; ++t) {
    float v0 = vb_bh[vo[0]+16*t], v1 = vb_bh[vo[1]+16*t],
          v2 = vb_bh[vo[2]+16*t], v3 = vb_bh[vo[3]+16*t];
    float v4=0.f, v5=0.f, v6=0.f, v7=0.f;
    if (!ACTIVE) { v4 = vb_bh[vo[4]+16*t]; v5 = vb_bh[vo[5]+16*t];
                   v6 = vb_bh[vo[6]+16*t]; v7 = vb_bh[vo[7]+16*t]; }
    vfr[t] = pack8(v0,v1,v2,v3,v4,v5,v6,v7);
  }

  float s8[8];
  if (!ACTIVE) {
    const int ka0 = k0 + 4*g, ka1 = k0 + 16 + 4*g;
    if (mbool) {
      unsigned w0 = *(const unsigned*)(m8_bh + (size_t)l15*LP + ka0);
      unsigned w1 = *(const unsigned*)(m8_bh + (size_t)l15*LP + ka1);
      #pragma unroll
      for (int j = 0; j < 4; ++j) {
        s8[j]   = ((w0>>(8*j))&0xFFu) ? sc0[j] : NEGBIG;
        s8[4+j] = ((w1>>(8*j))&0xFFu) ? sc1[j] : NEGBIG;
      }
    } else {
      int4 w0 = *(const int4*)(m32_bh + (size_t)l15*LP + ka0);
      int4 w1 = *(const int4*)(m32_bh + (size_t)l15*LP + ka1);
      s8[0]=w0.x?sc0[0]:NEGBIG; s8[1]=w0.y?sc0[1]:NEGBIG;
      s8[2]=w0.z?sc0[2]:NEGBIG; s8[3]=w0.w?sc0[3]:NEGBIG;
      s8[4]=w1.x?sc1[0]:NEGBIG; s8[5]=w1.y?sc1[1]:NEGBIG;
      s8[6]=w1.z?sc1[2]:NEGBIG; s8[7]=w1.w?sc1[3]:NEGBIG;
    }
  } else {
    #pragma unroll
    for (int j = 0; j < 4; ++j) { s8[j] = sc0[j]; s8[4+j] = NEGBIG; }
  }

  // online softmax in exp2 domain (QSC folded log2e into Q)
  float mx = fmaxf(fmaxf(fmaxf(s8[0],s8[1]),fmaxf(s8[2],s8[3])),
                   fmaxf(fmaxf(s8[4],s8[5]),fmaxf(s8[6],s8[7])));
  mx = fmaxf(mx, __shfl_xor(mx,16));
  mx = fmaxf(mx, __shfl_xor(mx,32));
  const float mn = fmaxf(m, mx);
  const float f = __builtin_amdgcn_exp2f(m - mn);
  float p[8], ps = 0.f;
  #pragma unroll
  for (int j = 0; j < 8; ++j){ p[j] = __builtin_amdgcn_exp2f(s8[j]-mn); ps += p[j]; }
  ps += __shfl_xor(ps,16);
  ps += __shfl_xor(ps,32);
  l = l * f + ps;
  m = mn;
  #pragma unroll
  for (int t = 0; t < 8; ++t){ acc[t][0]*=f; acc[t][1]*=f; acc[t][2]*=f; acc[t][3]*=f; }

  bf16x8 pf = pack8(p[0],p[1],p[2],p[3],p[4],p[5],p[6],p[7]);

  // ---- PV: all 8 MFMAs from staged bf16 V fragments ----
  #pragma unroll
  for (int t = 0; t < 8; ++t) {
    acc[t] = __builtin_amdgcn_mfma_f32_16x16x32_bf16(vfr[t], pf, acc[t], 0,0,0);
  }
}

__global__ __launch_bounds__(256, 4)
void attn_main(const float* __restrict__ Q, const float* __restrict__ Kp,
               const float* __restrict__ Vp, const float* __restrict__ Ka,
               const float* __restrict__ Va, const void* __restrict__ mask,
               float* __restrict__ out, float* __restrict__ dn)
{
  const int tid = threadIdx.x;
  const int lane = tid & 63;
  const int wid = tid >> 6;
  const int pair = wid >> 1, dh = wid & 1;
  const int bh = blockIdx.x >> 2;
  const int pg = (blockIdx.x & 3) * 2 + pair;   // pair-global: 0..7 (512 rows each)
  const int l15 = lane & 15, g = lane >> 4;

  // mask dtype probe: bytes 4i+1 are all-zero iff mask is int32-encoded
  const unsigned char* m8all = (const unsigned char*)mask;
  unsigned probe = 0;
  for (int i = lane; i < 256; i += 64) probe |= m8all[4*i+1];
  const bool mbool = (__any(probe != 0) != 0);

  // Q fragments (B-operand), scale folded in
  const float* qb = Q + ((size_t)bh*LQ + l15)*DD + 8*g;
  bf16x8 qf[8];
  #pragma unroll
  for (int s = 0; s < 8; ++s) {
    float4 a = *(const float4*)(qb + 32*s);
    float4 b = *(const float4*)(qb + 32*s + 4);
    qf[s] = pack8(a.x*QSC,a.y*QSC,a.z*QSC,a.w*QSC,
                  b.x*QSC,b.y*QSC,b.z*QSC,b.w*QSC);
  }

  f32x4 acc[8];
  #pragma unroll
  for (int t = 0; t < 8; ++t) acc[t] = (f32x4){0.f,0.f,0.f,0.f};
  float m = MINIT, l = 0.f;

  const float* kb_bh = Kp + (size_t)bh*LP*DD;
  const float* vb_bh = Vp + (size_t)bh*LP*DD;
  const unsigned char* m8_bh = m8all + (size_t)bh*LQ*LP;
  const int* m32_bh = (const int*)mask + (size_t)bh*LQ*LP;

  const int kbase = pg * 512;
  for (int c = 0; c < 16; ++c)
    chunk_body<false>(kb_bh, vb_bh, m8_bh, m32_bh, mbool,
                      kbase + 32*c, l15, g, dh, qf, acc, m, l);

  if (pg == 0)   // active K/V: one extra unmasked 16-row chunk
    chunk_body<true>(Ka + (size_t)bh*LQ*DD, Va + (size_t)bh*LQ*DD,
                     nullptr, nullptr, mbool, 0, l15, g, dh, qf, acc, m, l);

  // merge via fixed reference point R=0: logits*log2e is O(10), exp2 safe
  const float w = __builtin_amdgcn_exp2f(m);
  float* ob = out + ((size_t)bh*LQ + l15)*DD + dh*128 + 4*g;
  #pragma unroll
  for (int t = 0; t < 8; ++t) {
    atomicAdd(ob + 16*t + 0, w*acc[t][0]);
    atomicAdd(ob + 16*t + 1, w*acc[t][1]);
    atomicAdd(ob + 16*t + 2, w*acc[t][2]);
    atomicAdd(ob + 16*t + 3, w*acc[t][3]);
  }
  if (dh == 0 && g == 0)
    atomicAdd(dn + bh*LQ + l15, w*l);
}

__global__ void attn_norm(float* __restrict__ out, const float* __restrict__ dn)
{
  const int e = blockIdx.x * 256 + threadIdx.x;
  out[e] = out[e] / dn[e >> 8];
}

extern "C" void kernel_launch(void* const* d_in, const int* in_sizes, int n_in,
                              void* d_out, int out_size, void* d_ws, size_t ws_size,
                              hipStream_t stream) {
  const float* Q  = (const float*)d_in[0];
  const float* Kp = (const float*)d_in[1];
  const float* Vp = (const float*)d_in[2];
  const float* Ka = (const float*)d_in[3];
  const float* Va = (const float*)d_in[4];
  const void* mask = d_in[5];
  float* out = (float*)d_out;
  float* dn  = (float*)d_ws;   // 256*16 floats = 16 KB

  hipMemsetAsync(out, 0, (size_t)out_size * sizeof(float), stream);
  hipMemsetAsync(dn, 0, NBH * LQ * sizeof(float), stream);
  attn_main<<<NBH*4, 256, 0, stream>>>(Q, Kp, Vp, Ka, Va, mask, out, dn);
  attn_norm<<<(NBH*LQ*DD)/256, 256, 0, stream>>>(out, dn);
}